// Round 10
// baseline (954.431 us; speedup 1.0000x reference)
//
#include <hip/hip_runtime.h>
#include <hip/hip_bf16.h>

#define BB 128
#define TT 512
#define EE 128
#define HH 256
#define MM 1024
#define CC 5

typedef _Float16 h2 __attribute__((ext_vector_type(2)));
typedef __fp16 f16x8 __attribute__((ext_vector_type(8)));
typedef __fp16 f16x2 __attribute__((ext_vector_type(2)));
typedef float  f32x4 __attribute__((ext_vector_type(4)));

struct alignas(8) H4 { h2 a, b; };      // 4 f16 = 8B

__device__ inline h2 mkh2(float a, float b) {
    return __builtin_bit_cast(h2, __builtin_amdgcn_cvt_pkrtz(a, b));
}

__device__ inline f16x8 pack8(float4 lo, float4 hi) {
    union { f16x2 h[4]; f16x8 v; } u;
    u.h[0] = __builtin_amdgcn_cvt_pkrtz(lo.x, lo.y);
    u.h[1] = __builtin_amdgcn_cvt_pkrtz(lo.z, lo.w);
    u.h[2] = __builtin_amdgcn_cvt_pkrtz(hi.x, hi.y);
    u.h[3] = __builtin_amdgcn_cvt_pkrtz(hi.z, hi.w);
    return u.v;
}

__device__ inline float fast_tanh(float x) {
    float e = __expf(2.0f * x);
    return 1.0f - 2.0f / (e + 1.0f);
}

// ---------------------------------------------------------------------------
// K1 (MFMA GEMM): u[b][ch][t] = bias[ch] + emb[x[b*T+t]] @ W_ih^T  (f16).
// t-minor layout so k_rnn register-stashes 8 steps per b128. (unchanged, R9-passing)
// ---------------------------------------------------------------------------
__global__ __launch_bounds__(256, 2)
void k_embed(const int* __restrict__ x,
             const float* __restrict__ emb, const float* __restrict__ W_ih,
             const float* __restrict__ b_ih, const float* __restrict__ b_hh,
             _Float16* __restrict__ u)
{
    const int tb   = blockIdx.x;
    const int tid  = threadIdx.x;
    const int wv   = tid >> 6;
    const int lane = tid & 63;
    const int l15  = lane & 15;
    const int quad = lane >> 4;

    __shared__ __align__(16) char lds[32 * 256];

    f16x8 bf[4][4];
    float bias[4];
    #pragma unroll
    for (int ct = 0; ct < 4; ++ct) {
        const int n = 64 * wv + 16 * ct + l15;
        const float* wp = W_ih + (size_t)n * EE;
        #pragma unroll
        for (int kc = 0; kc < 4; ++kc) {
            const float4* p = (const float4*)(wp + 32 * kc + 8 * quad);
            bf[ct][kc] = pack8(p[0], p[1]);
        }
        bias[ct] = b_ih[n] + b_hh[n];
    }

    {
        const int r = tid >> 3;
        const int s = tid & 7;
        const int tok = x[tb * 32 + r];
        const float4* ep = (const float4*)(emb + (size_t)tok * EE + 16 * s);
        float4 a = ep[0], b = ep[1], c = ep[2], d = ep[3];
        *(f16x8*)(lds + r * 256 + 32 * s)      = pack8(a, b);
        *(f16x8*)(lds + r * 256 + 32 * s + 16) = pack8(c, d);
    }
    __syncthreads();

    f32x4 acc[2][4];
    #pragma unroll
    for (int rt = 0; rt < 2; ++rt)
        #pragma unroll
        for (int ct = 0; ct < 4; ++ct)
            acc[rt][ct] = (f32x4){bias[ct], bias[ct], bias[ct], bias[ct]};

    #pragma unroll
    for (int kc = 0; kc < 4; ++kc) {
        const int ko = (32 * kc + 8 * quad) * 2;
        f16x8 a0 = *(const f16x8*)(lds + (l15)      * 256 + ko);
        f16x8 a1 = *(const f16x8*)(lds + (16 + l15) * 256 + ko);
        #pragma unroll
        for (int ct = 0; ct < 4; ++ct) {
            acc[0][ct] = __builtin_amdgcn_mfma_f32_16x16x32_f16(a0, bf[ct][kc], acc[0][ct], 0, 0, 0);
            acc[1][ct] = __builtin_amdgcn_mfma_f32_16x16x32_f16(a1, bf[ct][kc], acc[1][ct], 0, 0, 0);
        }
    }

    const int bb  = tb >> 4;
    const int tt0 = (tb & 15) * 32;
    #pragma unroll
    for (int rt = 0; rt < 2; ++rt) {
        #pragma unroll
        for (int ct = 0; ct < 4; ++ct) {
            const int ch   = 64 * wv + 16 * ct + l15;
            const int tloc = tt0 + 16 * rt + 4 * quad;
            H4 o;
            o.a = mkh2(acc[rt][ct][0], acc[rt][ct][1]);
            o.b = mkh2(acc[rt][ct][2], acc[rt][ct][3]);
            *(H4*)((char*)u + ((size_t)(bb * HH + ch) * TT + tloc) * 2) = o;
        }
    }
}

// ---------------------------------------------------------------------------
// K2 (MFMA scan): 16 chains/WG, 8 WGs, 256 thr, 1 wave/SIMD (512-VGPR budget).
// R9's algorithm verified correct; R9's perf bug was register spill to scratch
// (VGPR_Count 168 << ~290 live) caused by pointer arrays -> per-step scratch
// traffic drained by every barrier. This version is register-clean: scalar
// u-pointers, explicit accumulators, no address-taken locals.
// A = W_hh in 128 VGPRs (loaded once). B = h from LDS (swizzled, 8 b128/lane).
// C-init = u_t from a 2x8-step register stash (16 b128 per chunk, in flight
// across at most one barrier). tanh + activity mask -> f16 -> alternate LDS
// h buffer. 1 barrier/step. Leading fully-inactive 16-step chunks skipped.
// ---------------------------------------------------------------------------
__global__ __launch_bounds__(256, 1)
void k_rnn(const int* __restrict__ lengths, const float* __restrict__ W_hh,
           const _Float16* __restrict__ u, float* __restrict__ hn)
{
    const int b0   = blockIdx.x * 16;
    const int tid  = threadIdx.x;
    const int wv   = tid >> 6;
    const int lane = tid & 63;
    const int l15  = lane & 15;
    const int q    = lane >> 4;

    __shared__ __align__(16) char lds[2 * 8192];   // h double buffer, swizzled

    // A = W_hh fragments: A[m=l15][k=q*8+j] per (Mtile, Kfrag). 128 VGPRs.
    f16x8 A[4][8];
    #pragma unroll
    for (int mt = 0; mt < 4; ++mt) {
        const float* wr = W_hh + (size_t)(wv * 64 + mt * 16 + l15) * HH;
        #pragma unroll
        for (int kf = 0; kf < 8; ++kf) {
            const float4* p = (const float4*)(wr + kf * 32 + q * 8);
            A[mt][kf] = pack8(p[0], p[1]);
        }
    }

    const int t0v = TT - lengths[b0 + l15];   // chain l15 active iff t >= t0v
    int maxlen = 0;
    #pragma unroll
    for (int j = 0; j < 16; ++j) {
        int lj = lengths[b0 + j];
        maxlen = (lj > maxlen) ? lj : maxlen;
    }
    const int c2_0 = (TT - maxlen) >> 4;      // first 16-step chunk with work

    // u pointers (t-minor): lane's (chain=l15, ch = wv*64+mt*16+q*4+r)
    const size_t chbase = (size_t)(b0 + l15) * HH + wv * 64 + q * 4;
    const char* up0 = (const char*)u + (chbase +  0) * (TT * 2) + c2_0 * 32;
    const char* up1 = (const char*)u + (chbase + 16) * (TT * 2) + c2_0 * 32;
    const char* up2 = (const char*)u + (chbase + 32) * (TT * 2) + c2_0 * 32;
    const char* up3 = (const char*)u + (chbase + 48) * (TT * 2) + c2_0 * 32;

    // swizzled LDS offsets (R9-verified correct):
    int roff[8], woff[4];
    #pragma unroll
    for (int kf = 0; kf < 8; ++kf)
        roff[kf] = l15 * 512 + ((kf * 64 + q * 16 + l15 * 16) & 511);
    #pragma unroll
    for (int mt = 0; mt < 4; ++mt)
        woff[mt] = l15 * 512 + ((wv * 128 + mt * 32 + q * 8 + l15 * 16) & 511);

    {   // zero both h buffers (16 KB)
        float4 z = {0.f, 0.f, 0.f, 0.f};
        #pragma unroll
        for (int i = 0; i < 4; ++i) *(float4*)(lds + tid * 16 + i * 4096) = z;
    }
    __syncthreads();

    f16x8 sA[16], sB[16];
    const int TT2 = TT * 2;

#define LOADC(SX)                                                          \
    {  SX[0]  = *(const f16x8*)(up0);        SX[1]  = *(const f16x8*)(up0 + TT2);     \
       SX[2]  = *(const f16x8*)(up0 + 2*TT2); SX[3]  = *(const f16x8*)(up0 + 3*TT2);  \
       SX[4]  = *(const f16x8*)(up1);        SX[5]  = *(const f16x8*)(up1 + TT2);     \
       SX[6]  = *(const f16x8*)(up1 + 2*TT2); SX[7]  = *(const f16x8*)(up1 + 3*TT2);  \
       SX[8]  = *(const f16x8*)(up2);        SX[9]  = *(const f16x8*)(up2 + TT2);     \
       SX[10] = *(const f16x8*)(up2 + 2*TT2); SX[11] = *(const f16x8*)(up2 + 3*TT2);  \
       SX[12] = *(const f16x8*)(up3);        SX[13] = *(const f16x8*)(up3 + TT2);     \
       SX[14] = *(const f16x8*)(up3 + 2*TT2); SX[15] = *(const f16x8*)(up3 + 3*TT2);  \
       up0 += 16; up1 += 16; up2 += 16; up3 += 16; }

#define STORE1(AC, MT)                                                     \
    {  float v0 = act ? fast_tanh(AC[0]) : 0.f;                            \
       float v1 = act ? fast_tanh(AC[1]) : 0.f;                            \
       float v2 = act ? fast_tanh(AC[2]) : 0.f;                            \
       float v3 = act ? fast_tanh(AC[3]) : 0.f;                            \
       H4 o; o.a = mkh2(v0, v1); o.b = mkh2(v2, v3);                       \
       *(H4*)(lds + wro + woff[MT]) = o; }

#define DO8(SX, TBASE)                                                     \
    { _Pragma("unroll")                                                    \
      for (int s = 0; s < 8; ++s) {                                        \
        f32x4 ac0 = {(float)SX[0][s],  (float)SX[1][s],                    \
                     (float)SX[2][s],  (float)SX[3][s]};                   \
        f32x4 ac1 = {(float)SX[4][s],  (float)SX[5][s],                    \
                     (float)SX[6][s],  (float)SX[7][s]};                   \
        f32x4 ac2 = {(float)SX[8][s],  (float)SX[9][s],                    \
                     (float)SX[10][s], (float)SX[11][s]};                  \
        f32x4 ac3 = {(float)SX[12][s], (float)SX[13][s],                   \
                     (float)SX[14][s], (float)SX[15][s]};                  \
        const int rdo = (s & 1) ? 8192 : 0;                                \
        _Pragma("unroll")                                                  \
        for (int kf = 0; kf < 8; ++kf) {                                   \
            f16x8 bfr = *(const f16x8*)(lds + rdo + roff[kf]);             \
            ac0 = __builtin_amdgcn_mfma_f32_16x16x32_f16(A[0][kf], bfr, ac0, 0, 0, 0); \
            ac1 = __builtin_amdgcn_mfma_f32_16x16x32_f16(A[1][kf], bfr, ac1, 0, 0, 0); \
            ac2 = __builtin_amdgcn_mfma_f32_16x16x32_f16(A[2][kf], bfr, ac2, 0, 0, 0); \
            ac3 = __builtin_amdgcn_mfma_f32_16x16x32_f16(A[3][kf], bfr, ac3, 0, 0, 0); \
        }                                                                  \
        const bool act = ((TBASE) + s >= t0v);                             \
        const int wro = (s & 1) ? 0 : 8192;                                \
        STORE1(ac0, 0) STORE1(ac1, 1) STORE1(ac2, 2) STORE1(ac3, 3)        \
        __syncthreads();                                                   \
      } }

    if (c2_0 < 32) {
        LOADC(sA);                       // first chunk
        for (int c2 = c2_0; c2 < 32; ++c2) {
            LOADC(sB);                   // next chunk, in flight over DO8
            DO8(sA, c2 * 16);
            if (c2 < 31) LOADC(sA);
            DO8(sB, c2 * 16 + 8);
        }
    }
#undef DO8
#undef STORE1
#undef LOADC

    // final h lives in buffer 0 (last step t=511 writes (511+1)&1 = 0)
    #pragma unroll
    for (int mt = 0; mt < 4; ++mt) {
        H4 hv = *(const H4*)(lds + woff[mt]);
        float4 o;
        o.x = (float)hv.a.x; o.y = (float)hv.a.y;
        o.z = (float)hv.b.x; o.w = (float)hv.b.y;
        *(float4*)(hn + (size_t)(b0 + l15) * HH + wv * 64 + mt * 16 + q * 4) = o;
    }
}

// ---------------------------------------------------------------------------
// K3: MLP head + log_softmax. One block per batch row. (unchanged)
// ---------------------------------------------------------------------------
__global__ __launch_bounds__(256, 2)
void k_head(const float* __restrict__ hn, const float* __restrict__ W0,
            const float* __restrict__ b0, const float* __restrict__ W1,
            const float* __restrict__ b1, float* __restrict__ out)
{
    const int b = blockIdx.x;
    const int tid = threadIdx.x;
    __shared__ float sh[HH];
    __shared__ float sh1[MM];
    __shared__ float sred[CC][4];
    __shared__ float slog[CC];

    sh[tid] = hn[(size_t)b * HH + tid];
    __syncthreads();

    float acc[4];
    #pragma unroll
    for (int i = 0; i < 4; ++i) acc[i] = b0[tid + 256 * i];
    const float4* sh4 = (const float4*)sh;
    for (int k4 = 0; k4 < HH / 4; ++k4) {
        float4 hv = sh4[k4];
        #pragma unroll
        for (int i = 0; i < 4; ++i) {
            float4 wv = ((const float4*)(W0 + (size_t)(tid + 256 * i) * HH))[k4];
            acc[i] += wv.x * hv.x + wv.y * hv.y + wv.z * hv.z + wv.w * hv.w;
        }
    }
    #pragma unroll
    for (int i = 0; i < 4; ++i) sh1[tid + 256 * i] = fmaxf(acc[i], 0.f);
    __syncthreads();

    float pc[CC] = {0.f, 0.f, 0.f, 0.f, 0.f};
    for (int k = tid; k < MM; k += 256) {
        float hv = sh1[k];
        #pragma unroll
        for (int c = 0; c < CC; ++c) pc[c] += W1[(size_t)c * MM + k] * hv;
    }
    const int lane = tid & 63, wid = tid >> 6;
    #pragma unroll
    for (int c = 0; c < CC; ++c) {
        float v = pc[c];
        #pragma unroll
        for (int off = 32; off > 0; off >>= 1) v += __shfl_down(v, off, 64);
        if (lane == 0) sred[c][wid] = v;
    }
    __syncthreads();
    if (tid < CC) {
        float s = sred[tid][0] + sred[tid][1] + sred[tid][2] + sred[tid][3]
                + b1[tid];
        slog[tid] = fmaxf(s, 0.f);
    }
    __syncthreads();
    if (tid < CC) {
        float mx = slog[0];
        #pragma unroll
        for (int c = 1; c < CC; ++c) mx = fmaxf(mx, slog[c]);
        float se = 0.f;
        #pragma unroll
        for (int c = 0; c < CC; ++c) se += __expf(slog[c] - mx);
        out[(size_t)b * CC + tid] = slog[tid] - mx - __logf(se);
    }
}

// ---------------------------------------------------------------------------
extern "C" void kernel_launch(void* const* d_in, const int* in_sizes, int n_in,
                              void* d_out, int out_size, void* d_ws, size_t ws_size,
                              hipStream_t stream) {
    const int*   x       = (const int*)d_in[0];
    const int*   lengths = (const int*)d_in[1];
    const float* emb     = (const float*)d_in[2];
    const float* W_ih    = (const float*)d_in[3];
    const float* W_hh    = (const float*)d_in[4];
    const float* b_ih    = (const float*)d_in[5];
    const float* b_hh    = (const float*)d_in[6];
    const float* W0      = (const float*)d_in[7];
    const float* b0      = (const float*)d_in[8];
    const float* W1      = (const float*)d_in[9];
    const float* b1      = (const float*)d_in[10];
    float* out = (float*)d_out;

    _Float16* u  = (_Float16*)d_ws;                       // [B][H][T] f16
    float*    hn = (float*)((char*)d_ws + (size_t)BB * TT * HH * sizeof(_Float16));

    k_embed<<<(BB * TT) / 32, 256, 0, stream>>>(x, emb, W_ih, b_ih, b_hh, u);
    k_rnn  <<<BB / 16, 256, 0, stream>>>(lengths, W_hh, u, hn);
    k_head <<<BB, 256, 0, stream>>>(hn, W0, b0, W1, b1, out);
}

// Round 11
// 715.316 us; speedup vs baseline: 1.3343x; 1.3343x over previous
//
#include <hip/hip_runtime.h>
#include <hip/hip_bf16.h>

#define BB 128
#define TT 512
#define EE 128
#define HH 256
#define MM 1024
#define CC 5

typedef _Float16 h2 __attribute__((ext_vector_type(2)));
typedef __fp16 f16x8 __attribute__((ext_vector_type(8)));
typedef __fp16 f16x2 __attribute__((ext_vector_type(2)));
typedef float  f32x4 __attribute__((ext_vector_type(4)));

struct alignas(8) H4 { h2 a, b; };      // 4 f16 = 8B

__device__ inline h2 mkh2(float a, float b) {
    return __builtin_bit_cast(h2, __builtin_amdgcn_cvt_pkrtz(a, b));
}

__device__ inline f16x8 pack8(float4 lo, float4 hi) {
    union { f16x2 h[4]; f16x8 v; } u;
    u.h[0] = __builtin_amdgcn_cvt_pkrtz(lo.x, lo.y);
    u.h[1] = __builtin_amdgcn_cvt_pkrtz(lo.z, lo.w);
    u.h[2] = __builtin_amdgcn_cvt_pkrtz(hi.x, hi.y);
    u.h[3] = __builtin_amdgcn_cvt_pkrtz(hi.z, hi.w);
    return u.v;
}

__device__ inline float fast_rcp(float x) {
#if __has_builtin(__builtin_amdgcn_rcpf)
    return __builtin_amdgcn_rcpf(x);   // v_rcp_f32: 1 trans op, ~1e-7 rel err
#else
    return 1.0f / x;
#endif
}

__device__ inline float fast_tanh(float x) {
    // tanh(x) = 1 - 2/(exp(2x)+1); exact at saturation. 2 trans ops total.
    float e = __expf(2.0f * x);
    return 1.0f - 2.0f * fast_rcp(e + 1.0f);
}

// ---------------------------------------------------------------------------
// K1 (MFMA GEMM): u[b][ch][t] = bias[ch] + emb[x[b*T+t]] @ W_ih^T  (f16).
// t-minor layout so k_rnn register-stashes 8 steps per b128. (R9/R10-passing)
// ---------------------------------------------------------------------------
__global__ __launch_bounds__(256, 2)
void k_embed(const int* __restrict__ x,
             const float* __restrict__ emb, const float* __restrict__ W_ih,
             const float* __restrict__ b_ih, const float* __restrict__ b_hh,
             _Float16* __restrict__ u)
{
    const int tb   = blockIdx.x;
    const int tid  = threadIdx.x;
    const int wv   = tid >> 6;
    const int lane = tid & 63;
    const int l15  = lane & 15;
    const int quad = lane >> 4;

    __shared__ __align__(16) char lds[32 * 256];

    f16x8 bf[4][4];
    float bias[4];
    #pragma unroll
    for (int ct = 0; ct < 4; ++ct) {
        const int n = 64 * wv + 16 * ct + l15;
        const float* wp = W_ih + (size_t)n * EE;
        #pragma unroll
        for (int kc = 0; kc < 4; ++kc) {
            const float4* p = (const float4*)(wp + 32 * kc + 8 * quad);
            bf[ct][kc] = pack8(p[0], p[1]);
        }
        bias[ct] = b_ih[n] + b_hh[n];
    }

    {
        const int r = tid >> 3;
        const int s = tid & 7;
        const int tok = x[tb * 32 + r];
        const float4* ep = (const float4*)(emb + (size_t)tok * EE + 16 * s);
        float4 a = ep[0], b = ep[1], c = ep[2], d = ep[3];
        *(f16x8*)(lds + r * 256 + 32 * s)      = pack8(a, b);
        *(f16x8*)(lds + r * 256 + 32 * s + 16) = pack8(c, d);
    }
    __syncthreads();

    f32x4 acc[2][4];
    #pragma unroll
    for (int rt = 0; rt < 2; ++rt)
        #pragma unroll
        for (int ct = 0; ct < 4; ++ct)
            acc[rt][ct] = (f32x4){bias[ct], bias[ct], bias[ct], bias[ct]};

    #pragma unroll
    for (int kc = 0; kc < 4; ++kc) {
        const int ko = (32 * kc + 8 * quad) * 2;
        f16x8 a0 = *(const f16x8*)(lds + (l15)      * 256 + ko);
        f16x8 a1 = *(const f16x8*)(lds + (16 + l15) * 256 + ko);
        #pragma unroll
        for (int ct = 0; ct < 4; ++ct) {
            acc[0][ct] = __builtin_amdgcn_mfma_f32_16x16x32_f16(a0, bf[ct][kc], acc[0][ct], 0, 0, 0);
            acc[1][ct] = __builtin_amdgcn_mfma_f32_16x16x32_f16(a1, bf[ct][kc], acc[1][ct], 0, 0, 0);
        }
    }

    const int bb  = tb >> 4;
    const int tt0 = (tb & 15) * 32;
    #pragma unroll
    for (int rt = 0; rt < 2; ++rt) {
        #pragma unroll
        for (int ct = 0; ct < 4; ++ct) {
            const int ch   = 64 * wv + 16 * ct + l15;
            const int tloc = tt0 + 16 * rt + 4 * quad;
            H4 o;
            o.a = mkh2(acc[rt][ct][0], acc[rt][ct][1]);
            o.b = mkh2(acc[rt][ct][2], acc[rt][ct][3]);
            *(H4*)((char*)u + ((size_t)(bb * HH + ch) * TT + tloc) * 2) = o;
        }
    }
}

// ---------------------------------------------------------------------------
// K2 (MFMA scan): 16 chains/WG, 8 WGs, 256 thr (4 waves, 1/SIMD).
// R10 post-mortem: algorithm correct but loop body was ~50KB (2 fully
// unrolled DO8s) -> L1I (32KB) thrash, plus exact-division tanh loading the
// trans pipe. This version: ONE 8-step DO8 per outer iteration
// (unroll-disabled outer loop, ~12KB body), u loaded 8 steps at a time
// (16 b128, drained once per 8 steps by the first barrier), rcp-based tanh.
// Layouts/swizzles verbatim from the R10-passing kernel.
// ---------------------------------------------------------------------------
__global__ __launch_bounds__(256, 1)
void k_rnn(const int* __restrict__ lengths, const float* __restrict__ W_hh,
           const _Float16* __restrict__ u, float* __restrict__ hn)
{
    const int b0   = blockIdx.x * 16;
    const int tid  = threadIdx.x;
    const int wv   = tid >> 6;
    const int lane = tid & 63;
    const int l15  = lane & 15;
    const int q    = lane >> 4;

    __shared__ __align__(16) char lds[2 * 8192];   // h double buffer, swizzled

    // A = W_hh fragments: A[m=l15][k=q*8+j] per (Mtile, Kfrag). 128 VGPRs.
    f16x8 A[4][8];
    #pragma unroll
    for (int mt = 0; mt < 4; ++mt) {
        const float* wr = W_hh + (size_t)(wv * 64 + mt * 16 + l15) * HH;
        #pragma unroll
        for (int kf = 0; kf < 8; ++kf) {
            const float4* p = (const float4*)(wr + kf * 32 + q * 8);
            A[mt][kf] = pack8(p[0], p[1]);
        }
    }

    const int t0v = TT - lengths[b0 + l15];   // chain l15 active iff t >= t0v
    int maxlen = 0;
    #pragma unroll
    for (int j = 0; j < 16; ++j) {
        int lj = lengths[b0 + j];
        maxlen = (lj > maxlen) ? lj : maxlen;
    }
    const int c8_0 = (TT - maxlen) >> 3;      // first 8-step chunk with work

    // u pointers (t-minor): lane's (chain=l15, ch = wv*64+mt*16+q*4+r)
    const size_t chbase = (size_t)(b0 + l15) * HH + wv * 64 + q * 4;
    const char* up0 = (const char*)u + (chbase +  0) * (TT * 2) + c8_0 * 16;
    const char* up1 = (const char*)u + (chbase + 16) * (TT * 2) + c8_0 * 16;
    const char* up2 = (const char*)u + (chbase + 32) * (TT * 2) + c8_0 * 16;
    const char* up3 = (const char*)u + (chbase + 48) * (TT * 2) + c8_0 * 16;

    // swizzled LDS offsets (R10-verified):
    int roff[8], woff[4];
    #pragma unroll
    for (int kf = 0; kf < 8; ++kf)
        roff[kf] = l15 * 512 + ((kf * 64 + q * 16 + l15 * 16) & 511);
    #pragma unroll
    for (int mt = 0; mt < 4; ++mt)
        woff[mt] = l15 * 512 + ((wv * 128 + mt * 32 + q * 8 + l15 * 16) & 511);

    {   // zero both h buffers (16 KB)
        float4 z = {0.f, 0.f, 0.f, 0.f};
        #pragma unroll
        for (int i = 0; i < 4; ++i) *(float4*)(lds + tid * 16 + i * 4096) = z;
    }
    __syncthreads();

    f16x8 sA[16];
    const int TT2 = TT * 2;

#define LOAD8                                                              \
    {  sA[0]  = *(const f16x8*)(up0);         sA[1]  = *(const f16x8*)(up0 + TT2);    \
       sA[2]  = *(const f16x8*)(up0 + 2*TT2); sA[3]  = *(const f16x8*)(up0 + 3*TT2);  \
       sA[4]  = *(const f16x8*)(up1);         sA[5]  = *(const f16x8*)(up1 + TT2);    \
       sA[6]  = *(const f16x8*)(up1 + 2*TT2); sA[7]  = *(const f16x8*)(up1 + 3*TT2);  \
       sA[8]  = *(const f16x8*)(up2);         sA[9]  = *(const f16x8*)(up2 + TT2);    \
       sA[10] = *(const f16x8*)(up2 + 2*TT2); sA[11] = *(const f16x8*)(up2 + 3*TT2);  \
       sA[12] = *(const f16x8*)(up3);         sA[13] = *(const f16x8*)(up3 + TT2);    \
       sA[14] = *(const f16x8*)(up3 + 2*TT2); sA[15] = *(const f16x8*)(up3 + 3*TT2);  \
       up0 += 16; up1 += 16; up2 += 16; up3 += 16; }

#define STORE1(AC, MT)                                                     \
    {  float v0 = act ? fast_tanh(AC[0]) : 0.f;                            \
       float v1 = act ? fast_tanh(AC[1]) : 0.f;                            \
       float v2 = act ? fast_tanh(AC[2]) : 0.f;                            \
       float v3 = act ? fast_tanh(AC[3]) : 0.f;                            \
       H4 o; o.a = mkh2(v0, v1); o.b = mkh2(v2, v3);                       \
       *(H4*)(lds + wro + woff[MT]) = o; }

    #pragma clang loop unroll(disable)
    for (int c8 = c8_0; c8 < 64; ++c8) {
        LOAD8;                          // 16 b128; drained by first barrier
        const int tb8 = c8 * 8;
        #pragma unroll
        for (int s = 0; s < 8; ++s) {
            f32x4 ac0 = {(float)sA[0][s],  (float)sA[1][s],
                         (float)sA[2][s],  (float)sA[3][s]};
            f32x4 ac1 = {(float)sA[4][s],  (float)sA[5][s],
                         (float)sA[6][s],  (float)sA[7][s]};
            f32x4 ac2 = {(float)sA[8][s],  (float)sA[9][s],
                         (float)sA[10][s], (float)sA[11][s]};
            f32x4 ac3 = {(float)sA[12][s], (float)sA[13][s],
                         (float)sA[14][s], (float)sA[15][s]};
            const int rdo = (s & 1) ? 8192 : 0;
            #pragma unroll
            for (int kf = 0; kf < 8; ++kf) {
                f16x8 bfr = *(const f16x8*)(lds + rdo + roff[kf]);
                ac0 = __builtin_amdgcn_mfma_f32_16x16x32_f16(A[0][kf], bfr, ac0, 0, 0, 0);
                ac1 = __builtin_amdgcn_mfma_f32_16x16x32_f16(A[1][kf], bfr, ac1, 0, 0, 0);
                ac2 = __builtin_amdgcn_mfma_f32_16x16x32_f16(A[2][kf], bfr, ac2, 0, 0, 0);
                ac3 = __builtin_amdgcn_mfma_f32_16x16x32_f16(A[3][kf], bfr, ac3, 0, 0, 0);
            }
            const bool act = (tb8 + s >= t0v);
            const int wro = (s & 1) ? 0 : 8192;
            STORE1(ac0, 0) STORE1(ac1, 1) STORE1(ac2, 2) STORE1(ac3, 3)
            __syncthreads();
        }
    }
#undef STORE1
#undef LOAD8

    // total steps even -> final h in buffer 0
    #pragma unroll
    for (int mt = 0; mt < 4; ++mt) {
        H4 hv = *(const H4*)(lds + woff[mt]);
        float4 o;
        o.x = (float)hv.a.x; o.y = (float)hv.a.y;
        o.z = (float)hv.b.x; o.w = (float)hv.b.y;
        *(float4*)(hn + (size_t)(b0 + l15) * HH + wv * 64 + mt * 16 + q * 4) = o;
    }
}

// ---------------------------------------------------------------------------
// K3: MLP head + log_softmax. One block per batch row. (unchanged)
// ---------------------------------------------------------------------------
__global__ __launch_bounds__(256, 2)
void k_head(const float* __restrict__ hn, const float* __restrict__ W0,
            const float* __restrict__ b0, const float* __restrict__ W1,
            const float* __restrict__ b1, float* __restrict__ out)
{
    const int b = blockIdx.x;
    const int tid = threadIdx.x;
    __shared__ float sh[HH];
    __shared__ float sh1[MM];
    __shared__ float sred[CC][4];
    __shared__ float slog[CC];

    sh[tid] = hn[(size_t)b * HH + tid];
    __syncthreads();

    float acc[4];
    #pragma unroll
    for (int i = 0; i < 4; ++i) acc[i] = b0[tid + 256 * i];
    const float4* sh4 = (const float4*)sh;
    for (int k4 = 0; k4 < HH / 4; ++k4) {
        float4 hv = sh4[k4];
        #pragma unroll
        for (int i = 0; i < 4; ++i) {
            float4 wv = ((const float4*)(W0 + (size_t)(tid + 256 * i) * HH))[k4];
            acc[i] += wv.x * hv.x + wv.y * hv.y + wv.z * hv.z + wv.w * hv.w;
        }
    }
    #pragma unroll
    for (int i = 0; i < 4; ++i) sh1[tid + 256 * i] = fmaxf(acc[i], 0.f);
    __syncthreads();

    float pc[CC] = {0.f, 0.f, 0.f, 0.f, 0.f};
    for (int k = tid; k < MM; k += 256) {
        float hv = sh1[k];
        #pragma unroll
        for (int c = 0; c < CC; ++c) pc[c] += W1[(size_t)c * MM + k] * hv;
    }
    const int lane = tid & 63, wid = tid >> 6;
    #pragma unroll
    for (int c = 0; c < CC; ++c) {
        float v = pc[c];
        #pragma unroll
        for (int off = 32; off > 0; off >>= 1) v += __shfl_down(v, off, 64);
        if (lane == 0) sred[c][wid] = v;
    }
    __syncthreads();
    if (tid < CC) {
        float s = sred[tid][0] + sred[tid][1] + sred[tid][2] + sred[tid][3]
                + b1[tid];
        slog[tid] = fmaxf(s, 0.f);
    }
    __syncthreads();
    if (tid < CC) {
        float mx = slog[0];
        #pragma unroll
        for (int c = 1; c < CC; ++c) mx = fmaxf(mx, slog[c]);
        float se = 0.f;
        #pragma unroll
        for (int c = 0; c < CC; ++c) se += __expf(slog[c] - mx);
        out[(size_t)b * CC + tid] = slog[tid] - mx - __logf(se);
    }
}

// ---------------------------------------------------------------------------
extern "C" void kernel_launch(void* const* d_in, const int* in_sizes, int n_in,
                              void* d_out, int out_size, void* d_ws, size_t ws_size,
                              hipStream_t stream) {
    const int*   x       = (const int*)d_in[0];
    const int*   lengths = (const int*)d_in[1];
    const float* emb     = (const float*)d_in[2];
    const float* W_ih    = (const float*)d_in[3];
    const float* W_hh    = (const float*)d_in[4];
    const float* b_ih    = (const float*)d_in[5];
    const float* b_hh    = (const float*)d_in[6];
    const float* W0      = (const float*)d_in[7];
    const float* b0      = (const float*)d_in[8];
    const float* W1      = (const float*)d_in[9];
    const float* b1      = (const float*)d_in[10];
    float* out = (float*)d_out;

    _Float16* u  = (_Float16*)d_ws;                       // [B][H][T] f16
    float*    hn = (float*)((char*)d_ws + (size_t)BB * TT * HH * sizeof(_Float16));

    k_embed<<<(BB * TT) / 32, 256, 0, stream>>>(x, emb, W_ih, b_ih, b_hh, u);
    k_rnn  <<<BB / 16, 256, 0, stream>>>(lengths, W_hh, u, hn);
    k_head <<<BB, 256, 0, stream>>>(hn, W0, b0, W1, b1, out);
}

// Round 12
// 595.573 us; speedup vs baseline: 1.6025x; 1.2011x over previous
//
#include <hip/hip_runtime.h>
#include <hip/hip_bf16.h>

#define BB 128
#define TT 512
#define EE 128
#define HH 256
#define MM 1024
#define CC 5

typedef _Float16 h2 __attribute__((ext_vector_type(2)));
typedef __fp16 f16x2 __attribute__((ext_vector_type(2)));
typedef __fp16 f16x8 __attribute__((ext_vector_type(8)));
typedef float  f32x4 __attribute__((ext_vector_type(4)));

__device__ inline h2 mkh2(float a, float b) {
    return __builtin_bit_cast(h2, __builtin_amdgcn_cvt_pkrtz(a, b));
}

__device__ inline f16x8 pack8(float4 lo, float4 hi) {
    union { f16x2 h[4]; f16x8 v; } u;
    u.h[0] = __builtin_amdgcn_cvt_pkrtz(lo.x, lo.y);
    u.h[1] = __builtin_amdgcn_cvt_pkrtz(lo.z, lo.w);
    u.h[2] = __builtin_amdgcn_cvt_pkrtz(hi.x, hi.y);
    u.h[3] = __builtin_amdgcn_cvt_pkrtz(hi.z, hi.w);
    return u.v;
}

__device__ inline float dot2f(h2 a, h2 b, float c) {
#if __has_builtin(__builtin_amdgcn_fdot2)
    return __builtin_amdgcn_fdot2(a, b, c, false);
#else
    return c + (float)a.x * (float)b.x + (float)a.y * (float)b.y;
#endif
}

// Quad butterfly sum via DPP (VALU pipe, no LDS traffic).
__device__ inline float dpp_add4(float x) {
    int t = __builtin_amdgcn_update_dpp(0, __builtin_bit_cast(int, x), 0xB1, 0xF, 0xF, true);
    x += __builtin_bit_cast(float, t);
    t = __builtin_amdgcn_update_dpp(0, __builtin_bit_cast(int, x), 0x4E, 0xF, 0xF, true);
    x += __builtin_bit_cast(float, t);
    return x;
}

__device__ inline float fast_rcp(float x) {
#if __has_builtin(__builtin_amdgcn_rcpf)
    return __builtin_amdgcn_rcpf(x);
#else
    return 1.0f / x;
#endif
}

__device__ inline float fast_tanh(float x) {
    float e = __expf(2.0f * x);
    return 1.0f - 2.0f * fast_rcp(e + 1.0f);
}

// ---------------------------------------------------------------------------
// K1 (MFMA GEMM): u[b][t][ch] = bias[ch] + emb[x[b*T+t]] @ W_ih^T  (f16,
// t-MAJOR). Verbatim from R7 (passed, off the top-5).
// ---------------------------------------------------------------------------
__global__ __launch_bounds__(256, 2)
void k_embed(const int* __restrict__ x,
             const float* __restrict__ emb, const float* __restrict__ W_ih,
             const float* __restrict__ b_ih, const float* __restrict__ b_hh,
             _Float16* __restrict__ u)
{
    const int tb   = blockIdx.x;
    const int tid  = threadIdx.x;
    const int wv   = tid >> 6;
    const int lane = tid & 63;
    const int l15  = lane & 15;
    const int quad = lane >> 4;

    __shared__ __align__(16) char lds[32 * 512];

    f16x8 bf[4][4];
    float bias[4];
    #pragma unroll
    for (int ct = 0; ct < 4; ++ct) {
        const int n = 64 * wv + 16 * ct + l15;
        const float* wp = W_ih + (size_t)n * EE;
        #pragma unroll
        for (int kc = 0; kc < 4; ++kc) {
            const float4* p = (const float4*)(wp + 32 * kc + 8 * quad);
            bf[ct][kc] = pack8(p[0], p[1]);
        }
        bias[ct] = b_ih[n] + b_hh[n];
    }

    {
        const int r = tid >> 3;
        const int s = tid & 7;
        const int tok = x[tb * 32 + r];
        const float4* ep = (const float4*)(emb + (size_t)tok * EE + 16 * s);
        float4 a = ep[0], b = ep[1], c = ep[2], d = ep[3];
        *(f16x8*)(lds + r * 256 + 32 * s)      = pack8(a, b);
        *(f16x8*)(lds + r * 256 + 32 * s + 16) = pack8(c, d);
    }
    __syncthreads();

    f32x4 acc[2][4];
    #pragma unroll
    for (int rt = 0; rt < 2; ++rt)
        #pragma unroll
        for (int ct = 0; ct < 4; ++ct)
            acc[rt][ct] = (f32x4){bias[ct], bias[ct], bias[ct], bias[ct]};

    #pragma unroll
    for (int kc = 0; kc < 4; ++kc) {
        const int ko = (32 * kc + 8 * quad) * 2;
        f16x8 a0 = *(const f16x8*)(lds + (l15)      * 256 + ko);
        f16x8 a1 = *(const f16x8*)(lds + (16 + l15) * 256 + ko);
        #pragma unroll
        for (int ct = 0; ct < 4; ++ct) {
            acc[0][ct] = __builtin_amdgcn_mfma_f32_16x16x32_f16(a0, bf[ct][kc], acc[0][ct], 0, 0, 0);
            acc[1][ct] = __builtin_amdgcn_mfma_f32_16x16x32_f16(a1, bf[ct][kc], acc[1][ct], 0, 0, 0);
        }
    }
    __syncthreads();

    #pragma unroll
    for (int rt = 0; rt < 2; ++rt) {
        #pragma unroll
        for (int ct = 0; ct < 4; ++ct) {
            const int chb = (64 * wv + 16 * ct + l15) * 2;
            #pragma unroll
            for (int rg = 0; rg < 4; ++rg) {
                const int tok = 16 * rt + 4 * quad + rg;
                *(_Float16*)(lds + tok * 512 + chb) = (_Float16)acc[rt][ct][rg];
            }
        }
    }
    __syncthreads();

    {
        char* dst = (char*)u + (size_t)tb * 16384 + tid * 64;
        const char* src = lds + tid * 64;
        #pragma unroll
        for (int q = 0; q < 4; ++q)
            *(float4*)(dst + 16 * q) = *(const float4*)(src + 16 * q);
    }
}

// ---------------------------------------------------------------------------
// K2: VALU scan (R6 structure, known 269 us) with ONE change: TWO independent
// chains per WG (512 thr; waves 0-3 = chain 0, waves 4-7 = chain 1; 2 waves
// per SIMD). Theory: R6's ~600 cyc/step residue (not LDS-pipe, not VALU
// issue, conflicts=0) is exposed latency from whole-CU lockstep on one chain;
// a co-resident independent chain fills those stall windows. Shared barriers
// have identical trip counts (common pair-max time base + per-chain activity
// mask; h stays 0 while masked, matching the right-aligned reference).
// ---------------------------------------------------------------------------
__global__ __launch_bounds__(512, 1)
void k_rnn(const int* __restrict__ lengths, const float* __restrict__ W_hh,
           const _Float16* __restrict__ u, float* __restrict__ hn)
{
    const int cg  = blockIdx.x;          // chain-pair
    const int tid = threadIdx.x;         // 0..511
    const int c   = tid >> 8;            // chain 0/1
    const int l   = tid & 255;           // local thread within chain
    const int b   = cg * 2 + c;
    const int kc  = l & 3;
    const int g   = l >> 2;

    const int len  = lengths[b];
    const int t0v  = TT - len;           // active iff t >= t0v
    const int lenA = lengths[cg * 2];
    const int lenB = lengths[cg * 2 + 1];
    const int maxlen = (lenA > lenB) ? lenA : lenB;
    const int cstart = (TT - maxlen) >> 6;   // first 64-step chunk with work

    // W_hh rows 4g..4g+3, cols [kc*64, kc*64+64) as f16 pairs: 128 VGPRs
    h2 w[4][32];
    #pragma unroll
    for (int m = 0; m < 4; ++m) {
        const float4* wr = (const float4*)(W_hh + (size_t)(4*g + m) * HH + kc*64);
        #pragma unroll
        for (int q = 0; q < 16; ++q) {
            float4 v = wr[q];
            w[m][2*q]   = mkh2(v.x, v.y);
            w[m][2*q+1] = mkh2(v.z, v.w);
        }
    }

    __shared__ char hbuf[2][2][512];               // [chain][buf] 256 f16
    __shared__ __align__(16) char ubuf[2][64*512]; // [chain] 64 steps x 512B
    ((float*)hbuf)[tid] = 0.f;                     // 512 floats = all 2KB

    // swizzled write slot for logical channel l (verbatim R6, tid->l)
    const int wr_off = (l >> 6) * 128
                     + (((((l >> 3) & 7) + 2 * (l >> 6)) & 7) << 4)
                     + ((l & 7) << 1);
    int roff[8];
    #pragma unroll
    for (int i = 0; i < 8; ++i)
        roff[i] = kc * 128 + (((i + 2 * kc) & 7) << 4);

    char* myh  = (char*)hbuf + c * 1024;           // + p*512
    char* myu  = (char*)ubuf + c * 32768;
    const char* ugl = (const char*)u + (size_t)b * TT * 512;  // t-major

    __syncthreads();

    float hlast = 0.f;
    int p = 0;
    for (int c64 = cstart; c64 < 8; ++c64) {
        // ---- stage 64 steps of u (32KB per chain), coalesced ----
        const int cb = c64 * 32768;
        float4 stash[8];
        #pragma unroll
        for (int q = 0; q < 8; ++q)
            stash[q] = *(const float4*)(ugl + cb + q * 4096 + l * 16);
        #pragma unroll
        for (int q = 0; q < 8; ++q)
            *(float4*)(myu + q * 4096 + l * 16) = stash[q];
        __syncthreads();
        // ---- 64 LDS-only steps ----
        const int tb64 = c64 * 64;
        for (int s = 0; s < 64; ++s) {
            const _Float16 uv = *(const _Float16*)(myu + s * 512 + l * 2);
            const char* hb = myh + p * 512;
            float a0 = 0.f, a1 = 0.f, a2 = 0.f, a3 = 0.f;
            #pragma unroll
            for (int i = 0; i < 8; ++i) {
                float4 hv = *(const float4*)(hb + roff[i]);
                h2* hp = (h2*)&hv;
                #pragma unroll
                for (int z = 0; z < 4; ++z) {
                    a0 = dot2f(w[0][4*i+z], hp[z], a0);
                    a1 = dot2f(w[1][4*i+z], hp[z], a1);
                    a2 = dot2f(w[2][4*i+z], hp[z], a2);
                    a3 = dot2f(w[3][4*i+z], hp[z], a3);
                }
            }
            a0 = dpp_add4(a0); a1 = dpp_add4(a1);
            a2 = dpp_add4(a2); a3 = dpp_add4(a3);
            float v = (kc == 0) ? a0 : (kc == 1) ? a1
                    : (kc == 2) ? a2 : a3;
            const bool act = (tb64 + s >= t0v);
            const float hnew = act ? fast_tanh(v + (float)uv) : 0.f;
            hlast = hnew;
            *(_Float16*)(myh + (p ^ 1) * 512 + wr_off) = (_Float16)hnew;
            __syncthreads();             // LDS-only inner loop: no vm drain
            p ^= 1;
        }
    }
    hn[(size_t)b * HH + l] = hlast;      // len==0 -> 0, matches ref
}

// ---------------------------------------------------------------------------
// K3: MLP head + log_softmax. One block per batch row. (unchanged)
// ---------------------------------------------------------------------------
__global__ __launch_bounds__(256, 2)
void k_head(const float* __restrict__ hn, const float* __restrict__ W0,
            const float* __restrict__ b0, const float* __restrict__ W1,
            const float* __restrict__ b1, float* __restrict__ out)
{
    const int b = blockIdx.x;
    const int tid = threadIdx.x;
    __shared__ float sh[HH];
    __shared__ float sh1[MM];
    __shared__ float sred[CC][4];
    __shared__ float slog[CC];

    sh[tid] = hn[(size_t)b * HH + tid];
    __syncthreads();

    float acc[4];
    #pragma unroll
    for (int i = 0; i < 4; ++i) acc[i] = b0[tid + 256 * i];
    const float4* sh4 = (const float4*)sh;
    for (int k4 = 0; k4 < HH / 4; ++k4) {
        float4 hv = sh4[k4];
        #pragma unroll
        for (int i = 0; i < 4; ++i) {
            float4 wv = ((const float4*)(W0 + (size_t)(tid + 256 * i) * HH))[k4];
            acc[i] += wv.x * hv.x + wv.y * hv.y + wv.z * hv.z + wv.w * hv.w;
        }
    }
    #pragma unroll
    for (int i = 0; i < 4; ++i) sh1[tid + 256 * i] = fmaxf(acc[i], 0.f);
    __syncthreads();

    float pc[CC] = {0.f, 0.f, 0.f, 0.f, 0.f};
    for (int k = tid; k < MM; k += 256) {
        float hv = sh1[k];
        #pragma unroll
        for (int c = 0; c < CC; ++c) pc[c] += W1[(size_t)c * MM + k] * hv;
    }
    const int lane = tid & 63, wid = tid >> 6;
    #pragma unroll
    for (int c = 0; c < CC; ++c) {
        float v = pc[c];
        #pragma unroll
        for (int off = 32; off > 0; off >>= 1) v += __shfl_down(v, off, 64);
        if (lane == 0) sred[c][wid] = v;
    }
    __syncthreads();
    if (tid < CC) {
        float s = sred[tid][0] + sred[tid][1] + sred[tid][2] + sred[tid][3]
                + b1[tid];
        slog[tid] = fmaxf(s, 0.f);
    }
    __syncthreads();
    if (tid < CC) {
        float mx = slog[0];
        #pragma unroll
        for (int c = 1; c < CC; ++c) mx = fmaxf(mx, slog[c]);
        float se = 0.f;
        #pragma unroll
        for (int c = 0; c < CC; ++c) se += __expf(slog[c] - mx);
        out[(size_t)b * CC + tid] = slog[tid] - mx - __logf(se);
    }
}

// ---------------------------------------------------------------------------
extern "C" void kernel_launch(void* const* d_in, const int* in_sizes, int n_in,
                              void* d_out, int out_size, void* d_ws, size_t ws_size,
                              hipStream_t stream) {
    const int*   x       = (const int*)d_in[0];
    const int*   lengths = (const int*)d_in[1];
    const float* emb     = (const float*)d_in[2];
    const float* W_ih    = (const float*)d_in[3];
    const float* W_hh    = (const float*)d_in[4];
    const float* b_ih    = (const float*)d_in[5];
    const float* b_hh    = (const float*)d_in[6];
    const float* W0      = (const float*)d_in[7];
    const float* b0      = (const float*)d_in[8];
    const float* W1      = (const float*)d_in[9];
    const float* b1      = (const float*)d_in[10];
    float* out = (float*)d_out;

    _Float16* u  = (_Float16*)d_ws;                       // [B][T][H] f16
    float*    hn = (float*)((char*)d_ws + (size_t)BB * TT * HH * sizeof(_Float16));

    k_embed<<<(BB * TT) / 32, 256, 0, stream>>>(x, emb, W_ih, b_ih, b_hh, u);
    k_rnn  <<<BB / 2, 512, 0, stream>>>(lengths, W_hh, u, hn);
    k_head <<<BB, 256, 0, stream>>>(hn, W0, b0, W1, b1, out);
}